// Round 1
// baseline (813.973 us; speedup 1.0000x reference)
//
#include <hip/hip_runtime.h>
#include <math.h>

#define SEQ  2048
#define NROW 16384   // 8 * 2048
#define HEAD 64
#define EMB  1024

// ---------------------------------------------------------------------------
// QKV projection. Block = 512 threads (8 waves), covers 64 rows of x (B*T flat).
// lane = row; wave w computes heads [24w, 24w+24) over q|k|v concatenated (192).
// W addresses are wave-uniform (readfirstlane) -> scalar s_load broadcast.
// Outputs: qT/kT transposed [h][grow] (coalesced writes, matches attn LDS
// layout), v normal [grow][h].
// ---------------------------------------------------------------------------
__global__ __launch_bounds__(512, 1) void qkv_proj_kernel(
    const float* __restrict__ x,
    const float* __restrict__ Wq,
    const float* __restrict__ Wk,
    const float* __restrict__ Wv,
    float* __restrict__ qT,
    float* __restrict__ kT,
    float* __restrict__ vN)
{
    const int tid  = threadIdx.x;
    const int wave = tid >> 6;
    const int lane = tid & 63;
    const int row  = blockIdx.x * 64 + lane;
    const int h0   = __builtin_amdgcn_readfirstlane(wave * 24);

    float acc[24];
#pragma unroll
    for (int i = 0; i < 24; ++i) acc[i] = 0.0f;

    const float* xrow = x + (size_t)row * EMB;

    for (int k0 = 0; k0 < EMB; k0 += 32) {
        float xr[32];
#pragma unroll
        for (int c = 0; c < 8; ++c) {
            float4 v4 = *(const float4*)(xrow + k0 + c * 4);
            xr[c * 4 + 0] = v4.x; xr[c * 4 + 1] = v4.y;
            xr[c * 4 + 2] = v4.z; xr[c * 4 + 3] = v4.w;
        }
#pragma unroll
        for (int hh = 0; hh < 24; ++hh) {
            const int h = h0 + hh;   // uniform per wave
            const float* Wrow;
            if (h < 64)       Wrow = Wq + (size_t)h * EMB;
            else if (h < 128) Wrow = Wk + (size_t)(h - 64) * EMB;
            else              Wrow = Wv + (size_t)(h - 128) * EMB;
            float a = acc[hh];
#pragma unroll
            for (int kk = 0; kk < 32; ++kk)
                a = fmaf(xr[kk], Wrow[k0 + kk], a);
            acc[hh] = a;
        }
    }

#pragma unroll
    for (int hh = 0; hh < 24; ++hh) {
        const int h = h0 + hh;
        if (h < 64)       qT[(size_t)h * NROW + row]          = acc[hh];
        else if (h < 128) kT[(size_t)(h - 64) * NROW + row]   = acc[hh];
        else              vN[(size_t)row * HEAD + (h - 128)]  = acc[hh];
    }
}

// ---------------------------------------------------------------------------
// Flash attention, fp32. Grid (32 qtiles, 8 batches), qt descending for load
// balance. Block = 256 threads: thread (tx=tid&15, ty=tid>>4) owns S/P rows
// 4ty+i, cols 4tx+j (and O rows 4ty+i, head dims 4tx+j).
// QsT/KsT stored [k][row] (pad 68: aligned b128, 2-way banks = free).
// ---------------------------------------------------------------------------
__global__ __launch_bounds__(256, 2) void attn_kernel(
    const float* __restrict__ qT,
    const float* __restrict__ kT,
    const float* __restrict__ vN,
    float* __restrict__ out)
{
    __shared__ float QsT[64][68];
    __shared__ float KsT[64][68];
    __shared__ float Vs [64][68];
    __shared__ float Ps [64][68];

    const int b   = blockIdx.y;
    const int qt  = (int)gridDim.x - 1 - (int)blockIdx.x;  // 31..0, big work first
    const int tid = threadIdx.x;
    const int tx  = tid & 15;
    const int ty  = tid >> 4;

    const int brow0 = b * SEQ;
    const int qrow0 = qt * 64;

    // Q tile -> LDS (already transposed in global: qT[h][grow])
#pragma unroll
    for (int j = 0; j < 4; ++j) {
        int idx = tid + 256 * j;
        int h   = idx >> 4;
        int s4  = (idx & 15) * 4;
        *(float4*)&QsT[h][s4] =
            *(const float4*)(qT + (size_t)h * NROW + brow0 + qrow0 + s4);
    }

    float o[4][4] = {};
    float m_i[4], l_i[4];
#pragma unroll
    for (int i = 0; i < 4; ++i) { m_i[i] = -INFINITY; l_i[i] = 0.0f; }

    for (int st = 0; st <= qt; ++st) {
        const int srow0 = st * 64;
        __syncthreads();   // previous iteration done with Ks/Vs/Ps

#pragma unroll
        for (int j = 0; j < 4; ++j) {
            int idx = tid + 256 * j;
            int h   = idx >> 4;
            int s4  = (idx & 15) * 4;
            *(float4*)&KsT[h][s4] =
                *(const float4*)(kT + (size_t)h * NROW + brow0 + srow0 + s4);
        }
#pragma unroll
        for (int j = 0; j < 4; ++j) {
            int idx = tid + 256 * j;
            int s   = idx >> 4;
            int h4  = (idx & 15) * 4;
            *(float4*)&Vs[s][h4] =
                *(const float4*)(vN + (size_t)(brow0 + srow0 + s) * HEAD + h4);
        }
        __syncthreads();

        // S = Q K^T (4x4 per thread)
        float sv[4][4] = {};
#pragma unroll 8
        for (int kk = 0; kk < 64; ++kk) {
            float4 qv = *(const float4*)&QsT[kk][4 * ty];  // broadcast (4 addrs)
            float4 kv = *(const float4*)&KsT[kk][4 * tx];  // 2-way banks, free
            const float* qa = &qv.x;
            const float* ka = &kv.x;
#pragma unroll
            for (int i = 0; i < 4; ++i)
#pragma unroll
                for (int j = 0; j < 4; ++j)
                    sv[i][j] = fmaf(qa[i], ka[j], sv[i][j]);
        }

        // scale + causal mask + online softmax
        const bool diag = (st == qt);
#pragma unroll
        for (int i = 0; i < 4; ++i) {
            const int grow = qrow0 + 4 * ty + i;
            float rmax = -INFINITY;
#pragma unroll
            for (int j = 0; j < 4; ++j) {
                float val = sv[i][j] * 0.125f;   // 1/sqrt(64)
                if (diag && (srow0 + 4 * tx + j) > grow) val = -INFINITY;
                sv[i][j] = val;
                rmax = fmaxf(rmax, val);
            }
#pragma unroll
            for (int mk = 1; mk <= 8; mk <<= 1)
                rmax = fmaxf(rmax, __shfl_xor(rmax, mk, 64));
            const float mnew  = fmaxf(m_i[i], rmax);   // finite: diag always has col<=row
            const float alpha = __expf(m_i[i] - mnew); // first tile: exp(-inf)=0
            m_i[i] = mnew;
            float lsum = 0.0f;
#pragma unroll
            for (int j = 0; j < 4; ++j) {
                float p = __expf(sv[i][j] - mnew);     // masked -> 0
                sv[i][j] = p;
                lsum += p;
            }
#pragma unroll
            for (int mk = 1; mk <= 8; mk <<= 1)
                lsum += __shfl_xor(lsum, mk, 64);
            l_i[i] = l_i[i] * alpha + lsum;
#pragma unroll
            for (int j = 0; j < 4; ++j) o[i][j] *= alpha;
        }

        // P -> LDS (normal layout, aligned float4 stores, 2-way banks)
#pragma unroll
        for (int i = 0; i < 4; ++i) {
            float4 pv = make_float4(sv[i][0], sv[i][1], sv[i][2], sv[i][3]);
            *(float4*)&Ps[4 * ty + i][4 * tx] = pv;
        }
        __syncthreads();

        // O += P V
#pragma unroll 4
        for (int s = 0; s < 64; ++s) {
            float4 vv = *(const float4*)&Vs[s][4 * tx];
            const float* va = &vv.x;
            float pr[4];
#pragma unroll
            for (int i = 0; i < 4; ++i) pr[i] = Ps[4 * ty + i][s];  // broadcast
#pragma unroll
            for (int i = 0; i < 4; ++i)
#pragma unroll
                for (int j = 0; j < 4; ++j)
                    o[i][j] = fmaf(pr[i], va[j], o[i][j]);
        }
    }

    // normalize + write out[b][t][h]
#pragma unroll
    for (int i = 0; i < 4; ++i) {
        const float inv = 1.0f / l_i[i];
        float4 ov = make_float4(o[i][0] * inv, o[i][1] * inv,
                                o[i][2] * inv, o[i][3] * inv);
        *(float4*)(out + ((size_t)brow0 + qrow0 + 4 * ty + i) * HEAD + 4 * tx) = ov;
    }
}

extern "C" void kernel_launch(void* const* d_in, const int* in_sizes, int n_in,
                              void* d_out, int out_size, void* d_ws, size_t ws_size,
                              hipStream_t stream)
{
    const float* x  = (const float*)d_in[0];
    const float* Wq = (const float*)d_in[1];
    const float* Wk = (const float*)d_in[2];
    const float* Wv = (const float*)d_in[3];

    float* qT = (float*)d_ws;                       // [64][16384]
    float* kT = qT + (size_t)HEAD * NROW;           // [64][16384]
    float* vN = kT + (size_t)HEAD * NROW;           // [16384][64]
    float* out = (float*)d_out;                     // [8][2048][64]

    qkv_proj_kernel<<<NROW / 64, 512, 0, stream>>>(x, Wq, Wk, Wv, qT, kT, vN);
    attn_kernel<<<dim3(32, 8), 256, 0, stream>>>(qT, kT, vN, out);
}

// Round 2
// 333.431 us; speedup vs baseline: 2.4412x; 2.4412x over previous
//
#include <hip/hip_runtime.h>
#include <math.h>

#define SEQ  2048
#define NROW 16384   // 8 * 2048
#define HEAD 64
#define EMB  1024

typedef __attribute__((ext_vector_type(8))) short short8;   // 8 bf16 = 4 VGPRs
typedef __attribute__((ext_vector_type(4))) float f32x4;    // MFMA 16x16 acc

// fp32 -> bf16 bits, round-to-nearest-even (inputs finite)
static __device__ __forceinline__ unsigned short f2bf(float f) {
    unsigned u = __builtin_bit_cast(unsigned, f);
    u += 0x7fffu + ((u >> 16) & 1u);
    return (unsigned short)(u >> 16);
}

// ---------------------------------------------------------------------------
// One-off: convert Wq|Wk|Wv (fp32 [64][1024] each) to contiguous bf16 [192][1024].
// ---------------------------------------------------------------------------
__global__ __launch_bounds__(256) void wcvt_kernel(
    const float* __restrict__ Wq, const float* __restrict__ Wk,
    const float* __restrict__ Wv, unsigned short* __restrict__ Wb)
{
    const int idx = (blockIdx.x * 256 + threadIdx.x) * 4;  // < 196608
    const int h = idx >> 10;
    const float* src;
    if (h < 64)       src = Wq + idx;
    else if (h < 128) src = Wk + (idx - 65536);
    else              src = Wv + (idx - 131072);
    float4 f = *(const float4*)src;
    ushort4 o;
    o.x = f2bf(f.x); o.y = f2bf(f.y); o.z = f2bf(f.z); o.w = f2bf(f.w);
    *(ushort4*)(Wb + idx) = o;
}

// ---------------------------------------------------------------------------
// QKV projection via bf16 MFMA. No LDS. Block = 256 thr = 4 waves:
// wave (w>>1) picks m-tile (16 rows), (w&1) picks head-half (96 heads = 6
// n-tiles of 16). Grid 512 blocks (32 rows each) -> 2048 waves, 2/SIMD.
// A-frag: x[m=lane&15][k=quad*8+j] fp32 -> bf16 in-register.
// B-frag: Wb[n=lane&15 + 16t][k] bf16 direct dwordx4.
// C/D: col=lane&15, row=quad*4+reg -> q/k float4 store into transposed
// qT/kT[h][row] layout; v scalar (coalesced across lanes) into vN[row][h].
// ---------------------------------------------------------------------------
__global__ __launch_bounds__(256, 2) void qkv_mfma_kernel(
    const float* __restrict__ x, const unsigned short* __restrict__ Wb,
    float* __restrict__ qT, float* __restrict__ kT, float* __restrict__ vN)
{
    const int tid   = threadIdx.x;
    const int w     = tid >> 6;
    const int lane  = tid & 63;
    const int col   = lane & 15;
    const int quad  = lane >> 4;
    const int mrow0 = blockIdx.x * 32 + (w >> 1) * 16;
    const int nhalf = w & 1;
    const int row   = mrow0 + col;

    const float* xp = x + (size_t)row * EMB + quad * 8;

    int hglob[6];
    const short8* bp[6];
#pragma unroll
    for (int t = 0; t < 6; ++t) {
        hglob[t] = nhalf * 96 + t * 16 + col;
        bp[t] = (const short8*)(Wb + (size_t)hglob[t] * EMB + quad * 8);
    }

    f32x4 acc[6];
#pragma unroll
    for (int t = 0; t < 6; ++t) acc[t] = (f32x4){0.f, 0.f, 0.f, 0.f};

#pragma unroll 4
    for (int ks = 0; ks < 32; ++ks) {          // k0 = 32*ks
        float4 a0 = *(const float4*)(xp + ks * 32);
        float4 a1 = *(const float4*)(xp + ks * 32 + 4);
        short8 af;
        af[0] = f2bf(a0.x); af[1] = f2bf(a0.y); af[2] = f2bf(a0.z); af[3] = f2bf(a0.w);
        af[4] = f2bf(a1.x); af[5] = f2bf(a1.y); af[6] = f2bf(a1.z); af[7] = f2bf(a1.w);
#pragma unroll
        for (int t = 0; t < 6; ++t) {
            short8 bf = bp[t][ks * 4];          // 32 shorts / kstep = 4 short8
            acc[t] = __builtin_amdgcn_mfma_f32_16x16x32_bf16(af, bf, acc[t], 0, 0, 0);
        }
    }

#pragma unroll
    for (int t = 0; t < 6; ++t) {
        const int h = hglob[t];
        if (h < 64) {
            *(f32x4*)(qT + (size_t)h * NROW + mrow0 + quad * 4) = acc[t];
        } else if (h < 128) {
            *(f32x4*)(kT + (size_t)(h - 64) * NROW + mrow0 + quad * 4) = acc[t];
        } else {
#pragma unroll
            for (int r = 0; r < 4; ++r)
                vN[(size_t)(mrow0 + quad * 4 + r) * HEAD + (h - 128)] = acc[t][r];
        }
    }
}

// ---------------------------------------------------------------------------
// Flash attention, fp32 (unchanged from round 1).
// ---------------------------------------------------------------------------
__global__ __launch_bounds__(256, 2) void attn_kernel(
    const float* __restrict__ qT,
    const float* __restrict__ kT,
    const float* __restrict__ vN,
    float* __restrict__ out)
{
    __shared__ float QsT[64][68];
    __shared__ float KsT[64][68];
    __shared__ float Vs [64][68];
    __shared__ float Ps [64][68];

    const int b   = blockIdx.y;
    const int qt  = (int)gridDim.x - 1 - (int)blockIdx.x;  // 31..0, big work first
    const int tid = threadIdx.x;
    const int tx  = tid & 15;
    const int ty  = tid >> 4;

    const int brow0 = b * SEQ;
    const int qrow0 = qt * 64;

#pragma unroll
    for (int j = 0; j < 4; ++j) {
        int idx = tid + 256 * j;
        int h   = idx >> 4;
        int s4  = (idx & 15) * 4;
        *(float4*)&QsT[h][s4] =
            *(const float4*)(qT + (size_t)h * NROW + brow0 + qrow0 + s4);
    }

    float o[4][4] = {};
    float m_i[4], l_i[4];
#pragma unroll
    for (int i = 0; i < 4; ++i) { m_i[i] = -INFINITY; l_i[i] = 0.0f; }

    for (int st = 0; st <= qt; ++st) {
        const int srow0 = st * 64;
        __syncthreads();

#pragma unroll
        for (int j = 0; j < 4; ++j) {
            int idx = tid + 256 * j;
            int h   = idx >> 4;
            int s4  = (idx & 15) * 4;
            *(float4*)&KsT[h][s4] =
                *(const float4*)(kT + (size_t)h * NROW + brow0 + srow0 + s4);
        }
#pragma unroll
        for (int j = 0; j < 4; ++j) {
            int idx = tid + 256 * j;
            int s   = idx >> 4;
            int h4  = (idx & 15) * 4;
            *(float4*)&Vs[s][h4] =
                *(const float4*)(vN + (size_t)(brow0 + srow0 + s) * HEAD + h4);
        }
        __syncthreads();

        float sv[4][4] = {};
#pragma unroll 8
        for (int kk = 0; kk < 64; ++kk) {
            float4 qv = *(const float4*)&QsT[kk][4 * ty];
            float4 kv = *(const float4*)&KsT[kk][4 * tx];
            const float* qa = &qv.x;
            const float* ka = &kv.x;
#pragma unroll
            for (int i = 0; i < 4; ++i)
#pragma unroll
                for (int j = 0; j < 4; ++j)
                    sv[i][j] = fmaf(qa[i], ka[j], sv[i][j]);
        }

        const bool diag = (st == qt);
#pragma unroll
        for (int i = 0; i < 4; ++i) {
            const int grow = qrow0 + 4 * ty + i;
            float rmax = -INFINITY;
#pragma unroll
            for (int j = 0; j < 4; ++j) {
                float val = sv[i][j] * 0.125f;
                if (diag && (srow0 + 4 * tx + j) > grow) val = -INFINITY;
                sv[i][j] = val;
                rmax = fmaxf(rmax, val);
            }
#pragma unroll
            for (int mk = 1; mk <= 8; mk <<= 1)
                rmax = fmaxf(rmax, __shfl_xor(rmax, mk, 64));
            const float mnew  = fmaxf(m_i[i], rmax);
            const float alpha = __expf(m_i[i] - mnew);
            m_i[i] = mnew;
            float lsum = 0.0f;
#pragma unroll
            for (int j = 0; j < 4; ++j) {
                float p = __expf(sv[i][j] - mnew);
                sv[i][j] = p;
                lsum += p;
            }
#pragma unroll
            for (int mk = 1; mk <= 8; mk <<= 1)
                lsum += __shfl_xor(lsum, mk, 64);
            l_i[i] = l_i[i] * alpha + lsum;
#pragma unroll
            for (int j = 0; j < 4; ++j) o[i][j] *= alpha;
        }

#pragma unroll
        for (int i = 0; i < 4; ++i) {
            float4 pv = make_float4(sv[i][0], sv[i][1], sv[i][2], sv[i][3]);
            *(float4*)&Ps[4 * ty + i][4 * tx] = pv;
        }
        __syncthreads();

#pragma unroll 4
        for (int s = 0; s < 64; ++s) {
            float4 vv = *(const float4*)&Vs[s][4 * tx];
            const float* va = &vv.x;
            float pr[4];
#pragma unroll
            for (int i = 0; i < 4; ++i) pr[i] = Ps[4 * ty + i][s];
#pragma unroll
            for (int i = 0; i < 4; ++i)
#pragma unroll
                for (int j = 0; j < 4; ++j)
                    o[i][j] = fmaf(pr[i], va[j], o[i][j]);
        }
    }

#pragma unroll
    for (int i = 0; i < 4; ++i) {
        const float inv = 1.0f / l_i[i];
        float4 ov = make_float4(o[i][0] * inv, o[i][1] * inv,
                                o[i][2] * inv, o[i][3] * inv);
        *(float4*)(out + ((size_t)brow0 + qrow0 + 4 * ty + i) * HEAD + 4 * tx) = ov;
    }
}

extern "C" void kernel_launch(void* const* d_in, const int* in_sizes, int n_in,
                              void* d_out, int out_size, void* d_ws, size_t ws_size,
                              hipStream_t stream)
{
    const float* x  = (const float*)d_in[0];
    const float* Wq = (const float*)d_in[1];
    const float* Wk = (const float*)d_in[2];
    const float* Wv = (const float*)d_in[3];

    float* qT = (float*)d_ws;                         // [64][16384] fp32, 4 MB
    float* kT = qT + (size_t)HEAD * NROW;             // [64][16384] fp32, 4 MB
    float* vN = kT + (size_t)HEAD * NROW;             // [16384][64] fp32, 4 MB
    unsigned short* Wb = (unsigned short*)(vN + (size_t)NROW * HEAD);  // [192][1024] bf16
    float* out = (float*)d_out;                       // [8][2048][64]

    wcvt_kernel<<<192, 256, 0, stream>>>(Wq, Wk, Wv, Wb);
    qkv_mfma_kernel<<<NROW / 32, 256, 0, stream>>>(x, Wb, qT, kT, vN);
    attn_kernel<<<dim3(32, 8), 256, 0, stream>>>(qT, kT, vN, out);
}

// Round 3
// 212.458 us; speedup vs baseline: 3.8312x; 1.5694x over previous
//
#include <hip/hip_runtime.h>
#include <math.h>

#define SEQ  2048
#define NROW 16384   // 8 * 2048
#define HEAD 64
#define EMB  1024

typedef __attribute__((ext_vector_type(8))) short short8;   // 8 bf16 = 4 VGPRs
typedef __attribute__((ext_vector_type(4))) float f32x4;    // MFMA 16x16 acc

// fp32 -> bf16 bits, round-to-nearest-even (inputs finite)
static __device__ __forceinline__ unsigned short f2bf(float f) {
    unsigned u = __builtin_bit_cast(unsigned, f);
    u += 0x7fffu + ((u >> 16) & 1u);
    return (unsigned short)(u >> 16);
}
static __device__ __forceinline__ float bf2f(unsigned short u) {
    unsigned v = (unsigned)u << 16;
    return __builtin_bit_cast(float, v);
}

// ---------------------------------------------------------------------------
// One-off: Wq|Wk|Wv fp32 [64][1024] -> contiguous bf16 [192][1024].
// ---------------------------------------------------------------------------
__global__ __launch_bounds__(256) void wcvt_kernel(
    const float* __restrict__ Wq, const float* __restrict__ Wk,
    const float* __restrict__ Wv, unsigned short* __restrict__ Wb)
{
    const int idx = (blockIdx.x * 256 + threadIdx.x) * 4;  // < 196608
    const int h = idx >> 10;
    const float* src;
    if (h < 64)       src = Wq + idx;
    else if (h < 128) src = Wk + (idx - 65536);
    else              src = Wv + (idx - 131072);
    float4 f = *(const float4*)src;
    ushort4 o;
    o.x = f2bf(f.x); o.y = f2bf(f.y); o.z = f2bf(f.z); o.w = f2bf(f.w);
    *(ushort4*)(Wb + idx) = o;
}

// ---------------------------------------------------------------------------
// QKV projection, bf16 MFMA, 2-deep register pipeline. Block = 256 thr =
// 4 waves: wave (w>>1) = m-sub (16 rows), (w&1) = head-half (6 n-tiles).
// Grid 512 blocks x 32 rows. Outputs bf16: qN[row][h], kN[row][h], vT[h][row]
// (exact MFMA A/B fragment layouts for the attention kernel).
// ---------------------------------------------------------------------------
__global__ __launch_bounds__(256, 2) void qkv_mfma_kernel(
    const float* __restrict__ x, const unsigned short* __restrict__ Wb,
    unsigned short* __restrict__ qN, unsigned short* __restrict__ kN,
    unsigned short* __restrict__ vT)
{
    const int tid   = threadIdx.x;
    const int w     = tid >> 6;
    const int lane  = tid & 63;
    const int col   = lane & 15;
    const int quad  = lane >> 4;
    const int row0  = blockIdx.x * 32 + (w >> 1) * 16;
    const int nhalf = w & 1;
    const int row   = row0 + col;

    const float*  xp  = x + (size_t)row * EMB + quad * 8;
    const short8* bp8 = (const short8*)(Wb + (size_t)(nhalf * 96 + col) * EMB + quad * 8);
    // tile t: +t*2048 short8;  k-step ks: +ks*4 short8

    f32x4 acc[6];
#pragma unroll
    for (int t = 0; t < 6; ++t) acc[t] = (f32x4){0.f, 0.f, 0.f, 0.f};

    float4 a0c, a1c, a0n, a1n;
    short8 bc[6], bn[6];

    a0c = *(const float4*)(xp);      a1c = *(const float4*)(xp + 4);
#pragma unroll
    for (int t = 0; t < 6; ++t) bc[t] = bp8[t * 2048];
    a0n = *(const float4*)(xp + 32); a1n = *(const float4*)(xp + 36);
#pragma unroll
    for (int t = 0; t < 6; ++t) bn[t] = bp8[t * 2048 + 4];

#pragma unroll 2
    for (int ks = 0; ks < 32; ++ks) {
        short8 af;
        af[0] = f2bf(a0c.x); af[1] = f2bf(a0c.y); af[2] = f2bf(a0c.z); af[3] = f2bf(a0c.w);
        af[4] = f2bf(a1c.x); af[5] = f2bf(a1c.y); af[6] = f2bf(a1c.z); af[7] = f2bf(a1c.w);
        short8 bu[6];
#pragma unroll
        for (int t = 0; t < 6; ++t) bu[t] = bc[t];
        // rotate pipeline
        a0c = a0n; a1c = a1n;
#pragma unroll
        for (int t = 0; t < 6; ++t) bc[t] = bn[t];
        if (ks + 2 < 32) {
            a0n = *(const float4*)(xp + (ks + 2) * 32);
            a1n = *(const float4*)(xp + (ks + 2) * 32 + 4);
#pragma unroll
            for (int t = 0; t < 6; ++t) bn[t] = bp8[t * 2048 + (ks + 2) * 4];
        }
#pragma unroll
        for (int t = 0; t < 6; ++t)
            acc[t] = __builtin_amdgcn_mfma_f32_16x16x32_bf16(af, bu[t], acc[t], 0, 0, 0);
    }

#pragma unroll
    for (int t = 0; t < 6; ++t) {
        const int hb = nhalf * 96 + 16 * t;   // tile base head (wave-uniform)
        const int h  = hb + col;
        if (hb < 64) {
#pragma unroll
            for (int r = 0; r < 4; ++r)
                qN[(size_t)(row0 + quad * 4 + r) * HEAD + h] = f2bf(acc[t][r]);
        } else if (hb < 128) {
#pragma unroll
            for (int r = 0; r < 4; ++r)
                kN[(size_t)(row0 + quad * 4 + r) * HEAD + (h - 64)] = f2bf(acc[t][r]);
        } else {
            ushort4 uv;
            uv.x = f2bf(acc[t][0]); uv.y = f2bf(acc[t][1]);
            uv.z = f2bf(acc[t][2]); uv.w = f2bf(acc[t][3]);
            *(ushort4*)(vT + (size_t)(h - 128) * NROW + row0 + quad * 4) = uv;
        }
    }
}

// ---------------------------------------------------------------------------
// Flash attention, bf16 MFMA, one wave per block, BM=16, BK=64, split-K P=2.
// Grid (128 qtiles, 8 batches, 2 parts). Partials (o bf16, m/l fp32) merged
// by merge_kernel. LDS only for the P (C/D -> A-operand) transpose, 16x68 f32.
// ---------------------------------------------------------------------------
__global__ __launch_bounds__(64, 2) void attn_kernel(
    const unsigned short* __restrict__ qN,
    const unsigned short* __restrict__ kN,
    const unsigned short* __restrict__ vT,
    unsigned short* __restrict__ op,      // [2][NROW][HEAD] bf16 partial O
    float2* __restrict__ ml)              // [2][NROW] {m, l}
{
    __shared__ float Pl[16][68];

    const int qt  = 127 - (int)blockIdx.x;     // descending: big work first
    const int b   = blockIdx.y;
    const int p   = blockIdx.z;
    const int tid = threadIdx.x;
    const int col  = tid & 15;
    const int quad = tid >> 4;

    const int q0   = qt * 16;                  // batch-local
    const int q0g  = b * SEQ + q0;             // global row
    const int C    = (qt >> 2) + 1;            // kt tiles for this q-strip
    const int half = (C + 1) >> 1;
    const int kt0  = p ? half : 0;
    const int kt1  = p ? C : half;

    // Q A-fragments (A[m=col][k=quad*8+j+32s]), hoisted
    const short8* qp8 = (const short8*)qN + (size_t)(q0g + col) * 8;
    short8 aq0 = qp8[quad];
    short8 aq1 = qp8[quad + 4];

    f32x4 o[4];
#pragma unroll
    for (int t = 0; t < 4; ++t) o[t] = (f32x4){0.f, 0.f, 0.f, 0.f};
    float m_i[4], l_i[4];
#pragma unroll
    for (int r = 0; r < 4; ++r) { m_i[r] = -INFINITY; l_i[r] = 0.0f; }

    for (int kt = kt0; kt < kt1; ++kt) {
        const int s0  = kt * 64;               // batch-local
        const int s0g = b * SEQ + s0;
        const bool diag = (kt == C - 1);

        // K B-frags: B[n = s0+16t+col][k = quad*8+j+32st]
        short8 kf[4][2];
#pragma unroll
        for (int t = 0; t < 4; ++t) {
            const short8* kp8 = (const short8*)kN + (size_t)(s0g + 16 * t + col) * 8;
            kf[t][0] = kp8[quad];
            kf[t][1] = kp8[quad + 4];
        }
        // V B-frags: B[n = head 16tn+col][k = s-row quad*8+j+32st]
        short8 vf[4][2];
#pragma unroll
        for (int tn = 0; tn < 4; ++tn) {
            const short8* vp8 = (const short8*)vT + (size_t)(16 * tn + col) * 2048 + (s0g >> 3);
            vf[tn][0] = vp8[quad];
            vf[tn][1] = vp8[quad + 4];
        }

        // S = Q K^T
        f32x4 sv[4];
#pragma unroll
        for (int t = 0; t < 4; ++t) {
            sv[t] = (f32x4){0.f, 0.f, 0.f, 0.f};
            sv[t] = __builtin_amdgcn_mfma_f32_16x16x32_bf16(aq0, kf[t][0], sv[t], 0, 0, 0);
            sv[t] = __builtin_amdgcn_mfma_f32_16x16x32_bf16(aq1, kf[t][1], sv[t], 0, 0, 0);
        }

        // scale + mask + online softmax (rows = quad*4+r, cols in lanes)
        float pv[4][4];
#pragma unroll
        for (int r = 0; r < 4; ++r) {
            const int grow = q0 + quad * 4 + r;
            float rm = -INFINITY;
#pragma unroll
            for (int t = 0; t < 4; ++t) {
                float val = sv[t][r] * 0.125f;
                if (diag && (s0 + 16 * t + col > grow)) val = -INFINITY;
                pv[t][r] = val;
                rm = fmaxf(rm, val);
            }
            rm = fmaxf(rm, __shfl_xor(rm, 1, 16));
            rm = fmaxf(rm, __shfl_xor(rm, 2, 16));
            rm = fmaxf(rm, __shfl_xor(rm, 4, 16));
            rm = fmaxf(rm, __shfl_xor(rm, 8, 16));
            const float mnew  = fmaxf(m_i[r], rm);
            const float alpha = __expf(m_i[r] - mnew);
            m_i[r] = mnew;
            float ls = 0.0f;
#pragma unroll
            for (int t = 0; t < 4; ++t) {
                float e = __expf(pv[t][r] - mnew);
                pv[t][r] = e;
                ls += e;
            }
            ls += __shfl_xor(ls, 1, 16);
            ls += __shfl_xor(ls, 2, 16);
            ls += __shfl_xor(ls, 4, 16);
            ls += __shfl_xor(ls, 8, 16);
            l_i[r] = l_i[r] * alpha + ls;
#pragma unroll
            for (int tn = 0; tn < 4; ++tn) o[tn][r] *= alpha;
        }

        // P: C/D layout -> LDS -> A-operand layout (bf16)
#pragma unroll
        for (int t = 0; t < 4; ++t)
#pragma unroll
            for (int r = 0; r < 4; ++r)
                Pl[quad * 4 + r][16 * t + col] = pv[t][r];
        // same-wave LDS write->read: lgkmcnt handled by compiler, no barrier
        short8 pf[2];
#pragma unroll
        for (int st = 0; st < 2; ++st) {
            float4 pa = *(const float4*)&Pl[col][quad * 8 + 32 * st];
            float4 pb = *(const float4*)&Pl[col][quad * 8 + 32 * st + 4];
            pf[st][0] = f2bf(pa.x); pf[st][1] = f2bf(pa.y);
            pf[st][2] = f2bf(pa.z); pf[st][3] = f2bf(pa.w);
            pf[st][4] = f2bf(pb.x); pf[st][5] = f2bf(pb.y);
            pf[st][6] = f2bf(pb.z); pf[st][7] = f2bf(pb.w);
        }

        // O += P V
#pragma unroll
        for (int tn = 0; tn < 4; ++tn) {
            o[tn] = __builtin_amdgcn_mfma_f32_16x16x32_bf16(pf[0], vf[tn][0], o[tn], 0, 0, 0);
            o[tn] = __builtin_amdgcn_mfma_f32_16x16x32_bf16(pf[1], vf[tn][1], o[tn], 0, 0, 0);
        }
    }

    // store partials (bf16 o, fp32 m/l)
#pragma unroll
    for (int tn = 0; tn < 4; ++tn)
#pragma unroll
        for (int r = 0; r < 4; ++r)
            op[(size_t)(p * NROW + q0g + quad * 4 + r) * HEAD + 16 * tn + col] =
                f2bf(o[tn][r]);
    if (col == 0) {
#pragma unroll
        for (int r = 0; r < 4; ++r)
            ml[p * NROW + q0g + quad * 4 + r] = make_float2(m_i[r], l_i[r]);
    }
}

// ---------------------------------------------------------------------------
// Combine the two split-K partials: out = (sum_p e^{m_p-m} o_p) / (sum_p e^{m_p-m} l_p)
// ---------------------------------------------------------------------------
__global__ __launch_bounds__(256) void merge_kernel(
    const unsigned short* __restrict__ op, const float2* __restrict__ ml,
    float* __restrict__ out)
{
    const int idx = blockIdx.x * 256 + threadIdx.x;   // 262144 total
    const int row = idx >> 4;
    const int hc  = (idx & 15) * 4;

    float2 e0 = ml[row];
    float2 e1 = ml[NROW + row];
    float m  = fmaxf(e0.x, e1.x);
    float w0 = __expf(e0.x - m);
    float w1 = __expf(e1.x - m);
    float inv = 1.0f / (e0.y * w0 + e1.y * w1);

    ushort4 u0 = *(const ushort4*)(op + (size_t)row * HEAD + hc);
    ushort4 u1 = *(const ushort4*)(op + (size_t)(NROW + row) * HEAD + hc);
    float4 r;
    r.x = (bf2f(u0.x) * w0 + bf2f(u1.x) * w1) * inv;
    r.y = (bf2f(u0.y) * w0 + bf2f(u1.y) * w1) * inv;
    r.z = (bf2f(u0.z) * w0 + bf2f(u1.z) * w1) * inv;
    r.w = (bf2f(u0.w) * w0 + bf2f(u1.w) * w1) * inv;
    *(float4*)(out + (size_t)row * HEAD + hc) = r;
}

extern "C" void kernel_launch(void* const* d_in, const int* in_sizes, int n_in,
                              void* d_out, int out_size, void* d_ws, size_t ws_size,
                              hipStream_t stream)
{
    const float* x  = (const float*)d_in[0];
    const float* Wq = (const float*)d_in[1];
    const float* Wk = (const float*)d_in[2];
    const float* Wv = (const float*)d_in[3];

    char* w = (char*)d_ws;
    unsigned short* qN = (unsigned short*)w;                       // 2 MB
    unsigned short* kN = (unsigned short*)(w + (2u << 20));        // 2 MB
    unsigned short* vT = (unsigned short*)(w + (4u << 20));        // 2 MB
    unsigned short* Wb = (unsigned short*)(w + (6u << 20));        // 384 KB
    unsigned short* op = (unsigned short*)(w + (6u << 20) + 393216);   // 4 MB
    float2*         ml = (float2*)(w + (10u << 20) + 393216);      // 256 KB
    float* out = (float*)d_out;

    wcvt_kernel<<<192, 256, 0, stream>>>(Wq, Wk, Wv, Wb);
    qkv_mfma_kernel<<<512, 256, 0, stream>>>(x, Wb, qN, kN, vT);
    attn_kernel<<<dim3(128, 8, 2), 64, 0, stream>>>(qN, kN, vT, op, ml);
    merge_kernel<<<1024, 256, 0, stream>>>(op, ml, out);
}

// Round 4
// 207.101 us; speedup vs baseline: 3.9303x; 1.0259x over previous
//
#include <hip/hip_runtime.h>
#include <math.h>

#define SEQ  2048
#define NROW 16384   // 8 * 2048
#define HEAD 64
#define EMB  1024

typedef __attribute__((ext_vector_type(8))) short short8;   // 8 bf16 = 4 VGPRs
typedef __attribute__((ext_vector_type(4))) float f32x4;    // MFMA 16x16 acc

// fp32 -> bf16 bits, round-to-nearest-even (inputs finite)
static __device__ __forceinline__ unsigned short f2bf(float f) {
    unsigned u = __builtin_bit_cast(unsigned, f);
    u += 0x7fffu + ((u >> 16) & 1u);
    return (unsigned short)(u >> 16);
}
static __device__ __forceinline__ float bf2f(unsigned short u) {
    unsigned v = (unsigned)u << 16;
    return __builtin_bit_cast(float, v);
}
static __device__ __forceinline__ short8 cvt8(float4 a, float4 b) {
    short8 r;
    r[0] = f2bf(a.x); r[1] = f2bf(a.y); r[2] = f2bf(a.z); r[3] = f2bf(a.w);
    r[4] = f2bf(b.x); r[5] = f2bf(b.y); r[6] = f2bf(b.z); r[7] = f2bf(b.w);
    return r;
}

// ---------------------------------------------------------------------------
// One-off: Wq|Wk|Wv fp32 [64][1024] -> contiguous bf16 [192][1024].
// ---------------------------------------------------------------------------
__global__ __launch_bounds__(256) void wcvt_kernel(
    const float* __restrict__ Wq, const float* __restrict__ Wk,
    const float* __restrict__ Wv, unsigned short* __restrict__ Wb)
{
    const int idx = (blockIdx.x * 256 + threadIdx.x) * 4;  // < 196608
    const int h = idx >> 10;
    const float* src;
    if (h < 64)       src = Wq + idx;
    else if (h < 128) src = Wk + (idx - 65536);
    else              src = Wv + (idx - 131072);
    float4 f = *(const float4*)src;
    ushort4 o;
    o.x = f2bf(f.x); o.y = f2bf(f.y); o.z = f2bf(f.z); o.w = f2bf(f.w);
    *(ushort4*)(Wb + idx) = o;
}

// ---------------------------------------------------------------------------
// QKV projection, bf16 MFMA. Block = 256 thr = 4 waves; block covers 16 rows.
// wave: nhalf = w&1 (96 heads = 6 n-tiles), khalf = w>>1 (K 512 of 1024).
// Grid 1024 blocks -> 4096 waves (4/SIMD). K-halves reduced through LDS.
// Ping-pong 2-deep register pipeline on A (fp32 x, cvt in-reg) and B (bf16 W).
// Outputs bf16: qN[row][h], kN[row][h], vT[h][row] (MFMA A/B frag layouts).
// ---------------------------------------------------------------------------
__global__ __launch_bounds__(256, 4) void qkv_mfma_kernel(
    const float* __restrict__ x, const unsigned short* __restrict__ Wb,
    unsigned short* __restrict__ qN, unsigned short* __restrict__ kN,
    unsigned short* __restrict__ vT)
{
    __shared__ float red[2 * 16 * 100];   // [nhalf][row][head%96] stride 100

    const int tid   = threadIdx.x;
    const int w     = tid >> 6;
    const int lane  = tid & 63;
    const int col   = lane & 15;
    const int quad  = lane >> 4;
    const int nhalf = w & 1;
    const int khalf = w >> 1;
    const int row0  = blockIdx.x * 16;
    const int row   = row0 + col;

    const float*  xp  = x + (size_t)row * EMB + khalf * 512 + quad * 8;
    const short8* bp8 = (const short8*)(Wb + (size_t)(nhalf * 96 + col) * EMB
                                        + khalf * 512 + quad * 8);
    // tile t: +t*2048 short8;  k-step ks: +ks*4 short8   (16 k-steps of 32)

    f32x4 acc[6];
#pragma unroll
    for (int t = 0; t < 6; ++t) acc[t] = (f32x4){0.f, 0.f, 0.f, 0.f};

    float4 a00, a01, a10, a11;
    short8 b0[6], b1[6];
    a00 = *(const float4*)(xp);      a01 = *(const float4*)(xp + 4);
#pragma unroll
    for (int t = 0; t < 6; ++t) b0[t] = bp8[t * 2048];
    a10 = *(const float4*)(xp + 32); a11 = *(const float4*)(xp + 36);
#pragma unroll
    for (int t = 0; t < 6; ++t) b1[t] = bp8[t * 2048 + 4];

#pragma unroll
    for (int ks = 0; ks < 16; ks += 2) {
        short8 af0 = cvt8(a00, a01);
#pragma unroll
        for (int t = 0; t < 6; ++t)
            acc[t] = __builtin_amdgcn_mfma_f32_16x16x32_bf16(af0, b0[t], acc[t], 0, 0, 0);
        if (ks + 2 < 16) {
            a00 = *(const float4*)(xp + (ks + 2) * 32);
            a01 = *(const float4*)(xp + (ks + 2) * 32 + 4);
#pragma unroll
            for (int t = 0; t < 6; ++t) b0[t] = bp8[t * 2048 + (ks + 2) * 4];
        }
        short8 af1 = cvt8(a10, a11);
#pragma unroll
        for (int t = 0; t < 6; ++t)
            acc[t] = __builtin_amdgcn_mfma_f32_16x16x32_bf16(af1, b1[t], acc[t], 0, 0, 0);
        if (ks + 3 < 16) {
            a10 = *(const float4*)(xp + (ks + 3) * 32);
            a11 = *(const float4*)(xp + (ks + 3) * 32 + 4);
#pragma unroll
            for (int t = 0; t < 6; ++t) b1[t] = bp8[t * 2048 + (ks + 3) * 4];
        }
    }

    // K-half reduction through LDS
    if (khalf == 1) {
#pragma unroll
        for (int t = 0; t < 6; ++t)
#pragma unroll
            for (int r = 0; r < 4; ++r)
                red[nhalf * 1600 + (quad * 4 + r) * 100 + 16 * t + col] = acc[t][r];
    }
    __syncthreads();
    if (khalf == 0) {
#pragma unroll
        for (int t = 0; t < 6; ++t) {
            const int hb = nhalf * 96 + 16 * t;   // wave-uniform tile base head
            const int h  = hb + col;
            float v0[4];
#pragma unroll
            for (int r = 0; r < 4; ++r)
                v0[r] = acc[t][r] +
                        red[nhalf * 1600 + (quad * 4 + r) * 100 + 16 * t + col];
            if (hb < 64) {
#pragma unroll
                for (int r = 0; r < 4; ++r)
                    qN[(size_t)(row0 + quad * 4 + r) * HEAD + h] = f2bf(v0[r]);
            } else if (hb < 128) {
#pragma unroll
                for (int r = 0; r < 4; ++r)
                    kN[(size_t)(row0 + quad * 4 + r) * HEAD + (h - 64)] = f2bf(v0[r]);
            } else {
                ushort4 uv;
                uv.x = f2bf(v0[0]); uv.y = f2bf(v0[1]);
                uv.z = f2bf(v0[2]); uv.w = f2bf(v0[3]);
                *(ushort4*)(vT + (size_t)(h - 128) * NROW + row0 + quad * 4) = uv;
            }
        }
    }
}

// ---------------------------------------------------------------------------
// Flash attention, bf16 MFMA. Block = 128 thr = 2 waves sharing one q-tile
// (BM=16). kt strip split 4 ways: global part p (blockIdx.z, 2) x wave (2);
// the two waves' online-softmax states merge in LDS, one global partial per
// (qt,b,p) -> merge_kernel (P=2 layout, same ws as round 3).
// Grid (128, 8, 2) -> 4096 waves.
// ---------------------------------------------------------------------------
__global__ __launch_bounds__(128, 3) void attn_kernel(
    const unsigned short* __restrict__ qN,
    const unsigned short* __restrict__ kN,
    const unsigned short* __restrict__ vT,
    unsigned short* __restrict__ op,      // [2][NROW][HEAD] bf16 partial O
    float2* __restrict__ ml)              // [2][NROW] {m, l}
{
    __shared__ float Pl[2][16][68];   // per-wave P transpose buffer
    __shared__ float Om[16][68];      // wave-1 O exchange
    __shared__ float Ml[16][2];       // wave-1 m/l exchange

    const int qt   = 127 - (int)blockIdx.x;    // descending: big work first
    const int b    = blockIdx.y;
    const int p    = blockIdx.z;
    const int tid  = threadIdx.x;
    const int wv   = tid >> 6;
    const int lane = tid & 63;
    const int col  = lane & 15;
    const int quad = lane >> 4;

    const int q0  = qt * 16;                   // batch-local
    const int q0g = b * SEQ + q0;              // global row
    const int C   = (qt >> 2) + 1;             // kt tiles in this strip
    const int qi  = p * 2 + wv;                // quarter index 0..3
    const int kt0 = (C * qi) >> 2;
    const int kt1 = (C * (qi + 1)) >> 2;

    // Q A-fragments (A[m=col][k=quad*8+j+32s])
    const short8* qp8 = (const short8*)qN + (size_t)(q0g + col) * 8;
    short8 aq0 = qp8[quad];
    short8 aq1 = qp8[quad + 4];

    f32x4 o[4];
#pragma unroll
    for (int t = 0; t < 4; ++t) o[t] = (f32x4){0.f, 0.f, 0.f, 0.f};
    float m_i[4], l_i[4];
#pragma unroll
    for (int r = 0; r < 4; ++r) { m_i[r] = -INFINITY; l_i[r] = 0.0f; }

    for (int kt = kt0; kt < kt1; ++kt) {
        const int s0  = kt * 64;
        const int s0g = b * SEQ + s0;
        const bool diag = (kt == C - 1);

        short8 kf[4][2];
#pragma unroll
        for (int t = 0; t < 4; ++t) {
            const short8* kp8 = (const short8*)kN + (size_t)(s0g + 16 * t + col) * 8;
            kf[t][0] = kp8[quad];
            kf[t][1] = kp8[quad + 4];
        }
        short8 vf[4][2];
#pragma unroll
        for (int tn = 0; tn < 4; ++tn) {
            const short8* vp8 = (const short8*)vT + (size_t)(16 * tn + col) * 2048 + (s0g >> 3);
            vf[tn][0] = vp8[quad];
            vf[tn][1] = vp8[quad + 4];
        }

        f32x4 sv[4];
#pragma unroll
        for (int t = 0; t < 4; ++t) {
            sv[t] = (f32x4){0.f, 0.f, 0.f, 0.f};
            sv[t] = __builtin_amdgcn_mfma_f32_16x16x32_bf16(aq0, kf[t][0], sv[t], 0, 0, 0);
            sv[t] = __builtin_amdgcn_mfma_f32_16x16x32_bf16(aq1, kf[t][1], sv[t], 0, 0, 0);
        }

        float pv[4][4];
#pragma unroll
        for (int r = 0; r < 4; ++r) {
            const int grow = q0 + quad * 4 + r;
            float rm = -INFINITY;
#pragma unroll
            for (int t = 0; t < 4; ++t) {
                float val = sv[t][r] * 0.125f;
                if (diag && (s0 + 16 * t + col > grow)) val = -INFINITY;
                pv[t][r] = val;
                rm = fmaxf(rm, val);
            }
            rm = fmaxf(rm, __shfl_xor(rm, 1, 16));
            rm = fmaxf(rm, __shfl_xor(rm, 2, 16));
            rm = fmaxf(rm, __shfl_xor(rm, 4, 16));
            rm = fmaxf(rm, __shfl_xor(rm, 8, 16));
            const float mnew  = fmaxf(m_i[r], rm);
            const float alpha = __expf(m_i[r] - mnew);
            m_i[r] = mnew;
            float ls = 0.0f;
#pragma unroll
            for (int t = 0; t < 4; ++t) {
                float e = __expf(pv[t][r] - mnew);
                pv[t][r] = e;
                ls += e;
            }
            ls += __shfl_xor(ls, 1, 16);
            ls += __shfl_xor(ls, 2, 16);
            ls += __shfl_xor(ls, 4, 16);
            ls += __shfl_xor(ls, 8, 16);
            l_i[r] = l_i[r] * alpha + ls;
#pragma unroll
            for (int tn = 0; tn < 4; ++tn) o[tn][r] *= alpha;
        }

        // P: C/D layout -> LDS (per-wave buffer) -> A-operand layout (bf16)
#pragma unroll
        for (int t = 0; t < 4; ++t)
#pragma unroll
            for (int r = 0; r < 4; ++r)
                Pl[wv][quad * 4 + r][16 * t + col] = pv[t][r];
        short8 pf[2];
#pragma unroll
        for (int st = 0; st < 2; ++st) {
            float4 pa = *(const float4*)&Pl[wv][col][quad * 8 + 32 * st];
            float4 pb = *(const float4*)&Pl[wv][col][quad * 8 + 32 * st + 4];
            pf[st] = cvt8(pa, pb);
        }

#pragma unroll
        for (int tn = 0; tn < 4; ++tn) {
            o[tn] = __builtin_amdgcn_mfma_f32_16x16x32_bf16(pf[0], vf[tn][0], o[tn], 0, 0, 0);
            o[tn] = __builtin_amdgcn_mfma_f32_16x16x32_bf16(pf[1], vf[tn][1], o[tn], 0, 0, 0);
        }
    }

    // ---- intra-block merge of the two waves' online-softmax states ----
    if (wv == 1) {
#pragma unroll
        for (int tn = 0; tn < 4; ++tn)
#pragma unroll
            for (int r = 0; r < 4; ++r)
                Om[quad * 4 + r][16 * tn + col] = o[tn][r];
        if (col == 0) {
#pragma unroll
            for (int r = 0; r < 4; ++r) {
                Ml[quad * 4 + r][0] = m_i[r];
                Ml[quad * 4 + r][1] = l_i[r];
            }
        }
    }
    __syncthreads();
    if (wv == 0) {
        float wa[4], wb[4], ms[4], lm[4];
#pragma unroll
        for (int r = 0; r < 4; ++r) {
            const float mb = Ml[quad * 4 + r][0];
            const float lb = Ml[quad * 4 + r][1];
            ms[r] = fmaxf(m_i[r], mb);
            wa[r] = (m_i[r] > -INFINITY) ? __expf(m_i[r] - ms[r]) : 0.0f;
            wb[r] = (mb     > -INFINITY) ? __expf(mb     - ms[r]) : 0.0f;
            lm[r] = l_i[r] * wa[r] + lb * wb[r];
        }
#pragma unroll
        for (int tn = 0; tn < 4; ++tn)
#pragma unroll
            for (int r = 0; r < 4; ++r) {
                float ov = o[tn][r] * wa[r] + Om[quad * 4 + r][16 * tn + col] * wb[r];
                op[(size_t)(p * NROW + q0g + quad * 4 + r) * HEAD + 16 * tn + col] =
                    f2bf(ov);
            }
        if (col == 0) {
#pragma unroll
            for (int r = 0; r < 4; ++r)
                ml[p * NROW + q0g + quad * 4 + r] = make_float2(ms[r], lm[r]);
        }
    }
}

// ---------------------------------------------------------------------------
// Combine the two global partials.
// ---------------------------------------------------------------------------
__global__ __launch_bounds__(256) void merge_kernel(
    const unsigned short* __restrict__ op, const float2* __restrict__ ml,
    float* __restrict__ out)
{
    const int idx = blockIdx.x * 256 + threadIdx.x;   // 262144 total
    const int row = idx >> 4;
    const int hc  = (idx & 15) * 4;

    float2 e0 = ml[row];
    float2 e1 = ml[NROW + row];
    float m  = fmaxf(e0.x, e1.x);
    float w0 = (e0.x > -INFINITY) ? __expf(e0.x - m) : 0.0f;
    float w1 = (e1.x > -INFINITY) ? __expf(e1.x - m) : 0.0f;
    float inv = 1.0f / (e0.y * w0 + e1.y * w1);

    ushort4 u0 = *(const ushort4*)(op + (size_t)row * HEAD + hc);
    ushort4 u1 = *(const ushort4*)(op + (size_t)(NROW + row) * HEAD + hc);
    float4 r;
    r.x = (bf2f(u0.x) * w0 + bf2f(u1.x) * w1) * inv;
    r.y = (bf2f(u0.y) * w0 + bf2f(u1.y) * w1) * inv;
    r.z = (bf2f(u0.z) * w0 + bf2f(u1.z) * w1) * inv;
    r.w = (bf2f(u0.w) * w0 + bf2f(u1.w) * w1) * inv;
    *(float4*)(out + (size_t)row * HEAD + hc) = r;
}

extern "C" void kernel_launch(void* const* d_in, const int* in_sizes, int n_in,
                              void* d_out, int out_size, void* d_ws, size_t ws_size,
                              hipStream_t stream)
{
    const float* x  = (const float*)d_in[0];
    const float* Wq = (const float*)d_in[1];
    const float* Wk = (const float*)d_in[2];
    const float* Wv = (const float*)d_in[3];

    char* w = (char*)d_ws;
    unsigned short* qN = (unsigned short*)w;                       // 2 MB
    unsigned short* kN = (unsigned short*)(w + (2u << 20));        // 2 MB
    unsigned short* vT = (unsigned short*)(w + (4u << 20));        // 2 MB
    unsigned short* Wb = (unsigned short*)(w + (6u << 20));        // 384 KB
    unsigned short* op = (unsigned short*)(w + (6u << 20) + 393216);   // 4 MB
    float2*         ml = (float2*)(w + (10u << 20) + 393216);      // 256 KB
    float* out = (float*)d_out;

    wcvt_kernel<<<192, 256, 0, stream>>>(Wq, Wk, Wv, Wb);
    qkv_mfma_kernel<<<1024, 256, 0, stream>>>(x, Wb, qN, kN, vT);
    attn_kernel<<<dim3(128, 8, 2), 128, 0, stream>>>(qN, kN, vT, op, ml);
    merge_kernel<<<1024, 256, 0, stream>>>(op, ml, out);
}

// Round 5
// 165.202 us; speedup vs baseline: 4.9271x; 1.2536x over previous
//
#include <hip/hip_runtime.h>
#include <math.h>

#define SEQ  2048
#define NROW 16384   // 8 * 2048
#define HEAD 64
#define EMB  1024

typedef __attribute__((ext_vector_type(8))) short short8;   // 8 bf16 = 4 VGPRs
typedef __attribute__((ext_vector_type(4))) float f32x4;    // MFMA 16x16 acc

// fp32 -> bf16 bits, round-to-nearest-even (inputs finite)
static __device__ __forceinline__ unsigned short f2bf(float f) {
    unsigned u = __builtin_bit_cast(unsigned, f);
    u += 0x7fffu + ((u >> 16) & 1u);
    return (unsigned short)(u >> 16);
}
static __device__ __forceinline__ float bf2f(unsigned short u) {
    unsigned v = (unsigned)u << 16;
    return __builtin_bit_cast(float, v);
}
static __device__ __forceinline__ short8 cvt8(float4 a, float4 b) {
    short8 r;
    r[0] = f2bf(a.x); r[1] = f2bf(a.y); r[2] = f2bf(a.z); r[3] = f2bf(a.w);
    r[4] = f2bf(b.x); r[5] = f2bf(b.y); r[6] = f2bf(b.z); r[7] = f2bf(b.w);
    return r;
}

// ---------------------------------------------------------------------------
// One-off: Wq|Wk|Wv fp32 [64][1024] -> contiguous bf16 [192][1024].
// ---------------------------------------------------------------------------
__global__ __launch_bounds__(256) void wcvt_kernel(
    const float* __restrict__ Wq, const float* __restrict__ Wk,
    const float* __restrict__ Wv, unsigned short* __restrict__ Wb)
{
    const int idx = (blockIdx.x * 256 + threadIdx.x) * 4;  // < 196608
    const int h = idx >> 10;
    const float* src;
    if (h < 64)       src = Wq + idx;
    else if (h < 128) src = Wk + (idx - 65536);
    else              src = Wv + (idx - 131072);
    float4 f = *(const float4*)src;
    ushort4 o;
    o.x = f2bf(f.x); o.y = f2bf(f.y); o.z = f2bf(f.z); o.w = f2bf(f.w);
    *(ushort4*)(Wb + idx) = o;
}

// ---------------------------------------------------------------------------
// QKV projection, bf16 MFMA, LDS-staged (coalesced global reads; all frag
// reads from padded LDS, <=2-way bank aliasing = free).
// Block = 256 thr = 4 waves; tile BM=32 x BN=96, BK=64.
// wave: mhalf = w>>1 (16 rows), ntri = w&1 (3 n-tiles of 16 heads).
// Grid (512, 2): 512 row-blocks x 2 head-halves -> 1024 blocks, 4/CU.
// Outputs bf16: qN[row][h], kN[row][h], vT[h][row] (MFMA A/B frag layouts).
// ---------------------------------------------------------------------------
__global__ __launch_bounds__(256, 4) void qkv_mfma_kernel(
    const float* __restrict__ x, const unsigned short* __restrict__ Wb,
    unsigned short* __restrict__ qN, unsigned short* __restrict__ kN,
    unsigned short* __restrict__ vT)
{
    __shared__ float          As[32][66];   // 8.25 KB, pad 66: 2-way banks
    __shared__ unsigned short Bs[96][68];   // 12.75 KB, pad 68: 2-way banks

    const int tid   = threadIdx.x;
    const int w     = tid >> 6;
    const int lane  = tid & 63;
    const int col   = lane & 15;
    const int quad  = lane >> 4;
    const int mhalf = w >> 1;
    const int ntri  = w & 1;
    const int row0  = blockIdx.x * 32;
    const int ny    = blockIdx.y;           // which 96-head half

    f32x4 acc[3];
#pragma unroll
    for (int t = 0; t < 3; ++t) acc[t] = (f32x4){0.f, 0.f, 0.f, 0.f};

    for (int k0 = 0; k0 < EMB; k0 += 64) {
        __syncthreads();   // previous iteration done reading As/Bs
        // stage A tile: 32 rows x 64 k fp32 (wave reads 4 rows x 256 B, coalesced)
#pragma unroll
        for (int rd = 0; rd < 2; ++rd) {
            int flat = rd * 256 + tid;          // 16-B chunk id
            int r = flat >> 4, c = flat & 15;
            float4 v = *(const float4*)(x + (size_t)(row0 + r) * EMB + k0 + c * 4);
            *(float4*)&As[r][c * 4] = v;
        }
        // stage B tile: 96 heads x 64 k bf16 (8 lanes x 128 B per head row)
#pragma unroll
        for (int rd = 0; rd < 3; ++rd) {
            int flat = rd * 256 + tid;          // 16-B chunk id (8 shorts)
            int h = flat >> 3, c = flat & 7;
            short8 v = *(const short8*)(Wb + (size_t)(ny * 96 + h) * EMB + k0 + c * 8);
            *(short8*)&Bs[h][c * 8] = v;
        }
        __syncthreads();
        // compute: 2 MFMA k-steps of 32
#pragma unroll
        for (int ks = 0; ks < 2; ++ks) {
            float4 a0 = *(const float4*)&As[mhalf * 16 + col][ks * 32 + quad * 8];
            float4 a1 = *(const float4*)&As[mhalf * 16 + col][ks * 32 + quad * 8 + 4];
            short8 af = cvt8(a0, a1);
#pragma unroll
            for (int t = 0; t < 3; ++t) {
                short8 bf = *(const short8*)&Bs[ntri * 48 + 16 * t + col][ks * 32 + quad * 8];
                acc[t] = __builtin_amdgcn_mfma_f32_16x16x32_bf16(af, bf, acc[t], 0, 0, 0);
            }
        }
    }

    // epilogue: heads hb = ny*96 + ntri*48 + 16t (all hb multiples of 16)
#pragma unroll
    for (int t = 0; t < 3; ++t) {
        const int hb = ny * 96 + ntri * 48 + 16 * t;   // wave-uniform
        const int h  = hb + col;
        const int ro = row0 + mhalf * 16 + quad * 4;
        if (hb < 64) {
#pragma unroll
            for (int r = 0; r < 4; ++r)
                qN[(size_t)(ro + r) * HEAD + h] = f2bf(acc[t][r]);
        } else if (hb < 128) {
#pragma unroll
            for (int r = 0; r < 4; ++r)
                kN[(size_t)(ro + r) * HEAD + (h - 64)] = f2bf(acc[t][r]);
        } else {
            ushort4 uv;
            uv.x = f2bf(acc[t][0]); uv.y = f2bf(acc[t][1]);
            uv.z = f2bf(acc[t][2]); uv.w = f2bf(acc[t][3]);
            *(ushort4*)(vT + (size_t)(h - 128) * NROW + ro) = uv;
        }
    }
}

// ---------------------------------------------------------------------------
// Flash attention, bf16 MFMA, LDS-staged K/V. Block = 256 thr = 4 waves
// sharing one 64-row q-tile; wave wv owns rows [q64+16wv, +16) -> no
// cross-wave state merge. K-tile/V-tile (64x64 bf16) staged coalesced per kt.
// Split-K P=2 (blockIdx.z) via op/ml partials + merge_kernel.
// Grid (32, 8, 2) = 512 blocks, qt descending.
// ---------------------------------------------------------------------------
__global__ __launch_bounds__(256, 2) void attn_kernel(
    const unsigned short* __restrict__ qN,
    const unsigned short* __restrict__ kN,
    const unsigned short* __restrict__ vT,
    unsigned short* __restrict__ op,      // [2][NROW][HEAD] bf16 partial O
    float2* __restrict__ ml)              // [2][NROW] {m, l}
{
    __shared__ unsigned short Ks[64][68];   // [key-row][head]  8.5 KB
    __shared__ unsigned short Vs[64][68];   // [head][key-row]  8.5 KB
    __shared__ float Pl[4][16][68];         // per-wave P transpose, 17 KB

    const int qt   = 31 - (int)blockIdx.x;     // descending: big work first
    const int b    = blockIdx.y;
    const int p    = blockIdx.z;
    const int tid  = threadIdx.x;
    const int wv   = tid >> 6;
    const int lane = tid & 63;
    const int col  = lane & 15;
    const int quad = lane >> 4;

    const int q0   = qt * 64 + wv * 16;        // wave's q rows (batch-local)
    const int q0g  = b * SEQ + q0;
    const int Cb   = qt + 1;                   // kt tiles (block-uniform)
    const int half = (Cb + 1) >> 1;
    const int kt0  = p ? half : 0;
    const int kt1  = p ? Cb : half;

    // Q A-fragments, direct (once per wave)
    const short8* qp8 = (const short8*)qN + (size_t)(q0g + col) * 8;
    short8 aq0 = qp8[quad];
    short8 aq1 = qp8[quad + 4];

    f32x4 o[4];
#pragma unroll
    for (int t = 0; t < 4; ++t) o[t] = (f32x4){0.f, 0.f, 0.f, 0.f};
    float m_i[4], l_i[4];
#pragma unroll
    for (int r = 0; r < 4; ++r) { m_i[r] = -INFINITY; l_i[r] = 0.0f; }

    for (int kt = kt0; kt < kt1; ++kt) {
        const int s0  = kt * 64;
        const int s0g = b * SEQ + s0;
        const bool diag = (kt == Cb - 1);

        __syncthreads();   // previous iteration done reading Ks/Vs
        // stage K tile: Ks[r][h] from kN (wave = 8 rows x 128 B, contiguous)
#pragma unroll
        for (int rd = 0; rd < 2; ++rd) {
            int flat = rd * 256 + tid;
            int r = flat >> 3, c = flat & 7;
            *(short8*)&Ks[r][c * 8] =
                *(const short8*)(kN + (size_t)(s0g + r) * HEAD + c * 8);
        }
        // stage V tile: Vs[h][s] from vT[h][NROW]
#pragma unroll
        for (int rd = 0; rd < 2; ++rd) {
            int flat = rd * 256 + tid;
            int h = flat >> 3, c = flat & 7;
            *(short8*)&Vs[h][c * 8] =
                *(const short8*)(vT + (size_t)h * NROW + s0g + c * 8);
        }
        __syncthreads();

        // S = Q K^T : B[n = key-row 16t+col][k = head]
        f32x4 sv[4];
#pragma unroll
        for (int t = 0; t < 4; ++t) {
            short8 kf0 = *(const short8*)&Ks[16 * t + col][quad * 8];
            short8 kf1 = *(const short8*)&Ks[16 * t + col][32 + quad * 8];
            sv[t] = (f32x4){0.f, 0.f, 0.f, 0.f};
            sv[t] = __builtin_amdgcn_mfma_f32_16x16x32_bf16(aq0, kf0, sv[t], 0, 0, 0);
            sv[t] = __builtin_amdgcn_mfma_f32_16x16x32_bf16(aq1, kf1, sv[t], 0, 0, 0);
        }

        // scale + causal mask + online softmax (rows = quad*4+r, cols in lanes)
        float pv[4][4];
#pragma unroll
        for (int r = 0; r < 4; ++r) {
            const int grow = q0 + quad * 4 + r;
            float rm = -INFINITY;
#pragma unroll
            for (int t = 0; t < 4; ++t) {
                float val = sv[t][r] * 0.125f;
                if (diag && (s0 + 16 * t + col > grow)) val = -INFINITY;
                pv[t][r] = val;
                rm = fmaxf(rm, val);
            }
            rm = fmaxf(rm, __shfl_xor(rm, 1, 16));
            rm = fmaxf(rm, __shfl_xor(rm, 2, 16));
            rm = fmaxf(rm, __shfl_xor(rm, 4, 16));
            rm = fmaxf(rm, __shfl_xor(rm, 8, 16));
            const float mnew  = fmaxf(m_i[r], rm);
            const float alpha = __expf(m_i[r] - mnew);
            m_i[r] = mnew;
            float ls = 0.0f;
#pragma unroll
            for (int t = 0; t < 4; ++t) {
                float e = __expf(pv[t][r] - mnew);
                pv[t][r] = e;
                ls += e;
            }
            ls += __shfl_xor(ls, 1, 16);
            ls += __shfl_xor(ls, 2, 16);
            ls += __shfl_xor(ls, 4, 16);
            ls += __shfl_xor(ls, 8, 16);
            l_i[r] = l_i[r] * alpha + ls;
#pragma unroll
            for (int tn = 0; tn < 4; ++tn) o[tn][r] *= alpha;
        }

        // P: C/D layout -> per-wave LDS buffer -> A-operand layout (bf16)
#pragma unroll
        for (int t = 0; t < 4; ++t)
#pragma unroll
            for (int r = 0; r < 4; ++r)
                Pl[wv][quad * 4 + r][16 * t + col] = pv[t][r];
        short8 pf[2];
#pragma unroll
        for (int st = 0; st < 2; ++st) {
            float4 pa = *(const float4*)&Pl[wv][col][quad * 8 + 32 * st];
            float4 pb = *(const float4*)&Pl[wv][col][quad * 8 + 32 * st + 4];
            pf[st] = cvt8(pa, pb);
        }

        // O += P V : B[n = head 16tn+col][k = key-row]
#pragma unroll
        for (int tn = 0; tn < 4; ++tn) {
            short8 vf0 = *(const short8*)&Vs[16 * tn + col][quad * 8];
            short8 vf1 = *(const short8*)&Vs[16 * tn + col][32 + quad * 8];
            o[tn] = __builtin_amdgcn_mfma_f32_16x16x32_bf16(pf[0], vf0, o[tn], 0, 0, 0);
            o[tn] = __builtin_amdgcn_mfma_f32_16x16x32_bf16(pf[1], vf1, o[tn], 0, 0, 0);
        }
    }

    // store this wave's partial (bf16 o, fp32 m/l)
#pragma unroll
    for (int tn = 0; tn < 4; ++tn)
#pragma unroll
        for (int r = 0; r < 4; ++r)
            op[(size_t)(p * NROW + q0g + quad * 4 + r) * HEAD + 16 * tn + col] =
                f2bf(o[tn][r]);
    if (col == 0) {
#pragma unroll
        for (int r = 0; r < 4; ++r)
            ml[p * NROW + q0g + quad * 4 + r] = make_float2(m_i[r], l_i[r]);
    }
}

// ---------------------------------------------------------------------------
// Combine the two split-K partials.
// ---------------------------------------------------------------------------
__global__ __launch_bounds__(256) void merge_kernel(
    const unsigned short* __restrict__ op, const float2* __restrict__ ml,
    float* __restrict__ out)
{
    const int idx = blockIdx.x * 256 + threadIdx.x;   // 262144 total
    const int row = idx >> 4;
    const int hc  = (idx & 15) * 4;

    float2 e0 = ml[row];
    float2 e1 = ml[NROW + row];
    float m  = fmaxf(e0.x, e1.x);
    float w0 = (e0.x > -INFINITY) ? __expf(e0.x - m) : 0.0f;
    float w1 = (e1.x > -INFINITY) ? __expf(e1.x - m) : 0.0f;
    float inv = 1.0f / (e0.y * w0 + e1.y * w1);

    ushort4 u0 = *(const ushort4*)(op + (size_t)row * HEAD + hc);
    ushort4 u1 = *(const ushort4*)(op + (size_t)(NROW + row) * HEAD + hc);
    float4 r;
    r.x = (bf2f(u0.x) * w0 + bf2f(u1.x) * w1) * inv;
    r.y = (bf2f(u0.y) * w0 + bf2f(u1.y) * w1) * inv;
    r.z = (bf2f(u0.z) * w0 + bf2f(u1.z) * w1) * inv;
    r.w = (bf2f(u0.w) * w0 + bf2f(u1.w) * w1) * inv;
    *(float4*)(out + (size_t)row * HEAD + hc) = r;
}

extern "C" void kernel_launch(void* const* d_in, const int* in_sizes, int n_in,
                              void* d_out, int out_size, void* d_ws, size_t ws_size,
                              hipStream_t stream)
{
    const float* x  = (const float*)d_in[0];
    const float* Wq = (const float*)d_in[1];
    const float* Wk = (const float*)d_in[2];
    const float* Wv = (const float*)d_in[3];

    char* w = (char*)d_ws;
    unsigned short* qN = (unsigned short*)w;                       // 2 MB
    unsigned short* kN = (unsigned short*)(w + (2u << 20));        // 2 MB
    unsigned short* vT = (unsigned short*)(w + (4u << 20));        // 2 MB
    unsigned short* Wb = (unsigned short*)(w + (6u << 20));        // 384 KB
    unsigned short* op = (unsigned short*)(w + (6u << 20) + 393216);   // 4 MB
    float2*         ml = (float2*)(w + (10u << 20) + 393216);      // 256 KB
    float* out = (float*)d_out;

    wcvt_kernel<<<192, 256, 0, stream>>>(Wq, Wk, Wv, Wb);
    qkv_mfma_kernel<<<dim3(512, 2), 256, 0, stream>>>(x, Wb, qN, kN, vT);
    attn_kernel<<<dim3(32, 8, 2), 256, 0, stream>>>(qN, kN, vT, op, ml);
    merge_kernel<<<1024, 256, 0, stream>>>(op, ml, out);
}